// Round 5
// baseline (208.383 us; speedup 1.0000x reference)
//
#include <hip/hip_runtime.h>
#include <hip/hip_bf16.h>

#define HH 256   // hidden dim
#define HJ 128   // H/2
#define GG 512   // number of graphs

typedef __attribute__((ext_vector_type(8))) short short8;
typedef __attribute__((ext_vector_type(4))) float f32x4;

static __device__ __forceinline__ short f2bf(float f) {
  // round-to-nearest-even fp32 -> bf16 (inputs are finite)
  unsigned u = __builtin_bit_cast(unsigned, f);
  unsigned r = (u + 0x7FFFu + ((u >> 16) & 1u)) >> 16;
  return (short)r;
}

static __device__ __forceinline__ float bf2f(short b) {
  unsigned u = ((unsigned)(unsigned short)b) << 16;
  return __builtin_bit_cast(float, u);
}

// ---------------- Kernel 0: pre-fragment W1^T into MFMA A-operand order ----
// w1a[kt*8+jt][lane] = 8 bf16: A[m=j][k] with j = jt*16+(l&15), k = kt*32+(l>>4)*8+i
__global__ __launch_bounds__(64) void w1frag_kernel(
    const float* __restrict__ W1, short8* __restrict__ w1a) {
  const int l = threadIdx.x;
  const int kt = blockIdx.x >> 3;
  const int jt = blockIdx.x & 7;
  const int j = jt * 16 + (l & 15);
  const int kb = kt * 32 + (l >> 4) * 8;
  short8 v;
#pragma unroll
  for (int i = 0; i < 8; ++i) v[i] = f2bf(W1[(size_t)(kb + i) * HJ + j]);
  w1a[blockIdx.x * 64 + l] = v;
}

// ---------------- segment offsets from sorted batch ----------------
__global__ __launch_bounds__(256) void segstart_kernel(
    const int* __restrict__ batch, int* __restrict__ segstart, int N, int G) {
  const int n = blockIdx.x * 256 + threadIdx.x;
  if (n >= N) return;
  const int b = batch[n];
  const int p = (n == 0) ? -1 : batch[n - 1];
  for (int g = p + 1; g <= b; ++g) segstart[g] = n;
  if (n == N - 1) {
    for (int g = b + 1; g <= G; ++g) segstart[g] = N;
  }
}

// ---------------- Kernel A: fused gate MLP + block-local pool --------------
// s[n] = tanh(x[n,:]@W1 + b1)@W2   (b2 dropped: softmax shift-invariant)
// e_n = exp(s_n)  (max-free: |s| <= ~10, fp32-safe)
// Block-local reduction of e_n*x[n,:] per graph-slot (<=4 graphs/block,
// batch sorted, segments ~390 nodes), spilled as ordinary coalesced partials.
__global__ __launch_bounds__(512) void gate_pool_kernel(
    const float* __restrict__ x, const short8* __restrict__ w1a,
    const float* __restrict__ b1, const float* __restrict__ W2,
    const int* __restrict__ batch, float* __restrict__ gpart,
    float* __restrict__ gpsum, int N) {
  __shared__ short8 alds[4096];  // 64 KB: A-frags, reused as pemb after MFMA
  __shared__ float pesum[8][4];
  const int tid = threadIdx.x;
  const int l = tid & 63;
  const int w = tid >> 6;  // wave 0..7

  // stage all A fragments (linear, coalesced, conflict-free)
#pragma unroll
  for (int i = 0; i < 8; ++i) alds[tid + i * 512] = w1a[tid + i * 512];

  const int base = blockIdx.x * 128;
  const int node = base + w * 16 + (l & 15);
  const bool valid = node < N;
  const float* xp = x + (size_t)node * HH + (l >> 4) * 8;

  // B fragments: lane holds x[node][kt*32 + (l>>4)*8 + 0..7] as bf16
  short8 bfrag[8];
#pragma unroll
  for (int kt = 0; kt < 8; ++kt) {
    float4 f0 = make_float4(0.f, 0.f, 0.f, 0.f), f1 = f0;
    if (valid) {
      f0 = *reinterpret_cast<const float4*>(xp + kt * 32);
      f1 = *reinterpret_cast<const float4*>(xp + kt * 32 + 4);
    }
    short8 v;
    v[0] = f2bf(f0.x); v[1] = f2bf(f0.y); v[2] = f2bf(f0.z); v[3] = f2bf(f0.w);
    v[4] = f2bf(f1.x); v[5] = f2bf(f1.y); v[6] = f2bf(f1.z); v[7] = f2bf(f1.w);
    bfrag[kt] = v;
  }
  __syncthreads();

  f32x4 acc[8];
#pragma unroll
  for (int jt = 0; jt < 8; ++jt) acc[jt] = (f32x4)(0.f);

#pragma unroll
  for (int kt = 0; kt < 8; ++kt) {
#pragma unroll
    for (int jt = 0; jt < 8; ++jt) {
      acc[jt] = __builtin_amdgcn_mfma_f32_16x16x32_bf16(
          alds[(kt * 8 + jt) * 64 + l], bfrag[kt], acc[jt], 0, 0, 0);
    }
  }

  // epilogue: lane holds h[j][node] for j = jt*16 + (l>>4)*4 + r
  float sacc = 0.f;
  const int jb = (l >> 4) * 4;
#pragma unroll
  for (int jt = 0; jt < 8; ++jt) {
    const int j0 = jt * 16 + jb;
    const float4 bb = *reinterpret_cast<const float4*>(b1 + j0);
    const float4 ww = *reinterpret_cast<const float4*>(W2 + j0);
    sacc += tanhf(acc[jt][0] + bb.x) * ww.x;
    sacc += tanhf(acc[jt][1] + bb.y) * ww.y;
    sacc += tanhf(acc[jt][2] + bb.z) * ww.z;
    sacc += tanhf(acc[jt][3] + bb.w) * ww.w;
  }
  sacc += __shfl_xor(sacc, 16, 64);
  sacc += __shfl_xor(sacc, 32, 64);
  // every lane now holds s for node (l&15)

  const float e = valid ? expf(sacc) : 0.f;
  const int myg = batch[valid ? node : (N - 1)];
  const int G0 = batch[base];
  const int gw0 = __shfl(myg, 0, 64);
  const int gw1 = __shfl(myg, 15, 64);

  __syncthreads();  // all MFMA reads of alds done; reuse as pemb
  float* pemb = (float*)alds;  // [wave(8)][slot(4)][256]

  // zero wave-private slots (16 stores/lane, conflict-free)
  {
    float* wp = pemb + w * 1024;
#pragma unroll
    for (int i = 0; i < 16; ++i) wp[i * 64 + l] = 0.f;
    if (l < 4) pesum[w][l] = 0.f;
  }
  // wave-private region: no barrier needed before writes below
  for (int g = gw0; g <= gw1; ++g) {
    const int j = g - G0;
    if (j < 0 || j > 3) continue;
    const float ew = (myg == g) ? e : 0.f;
    float es = ew;
    es += __shfl_xor(es, 1, 64);
    es += __shfl_xor(es, 2, 64);
    es += __shfl_xor(es, 4, 64);
    es += __shfl_xor(es, 8, 64);
    float* slot = pemb + (w * 4 + j) * 256;
#pragma unroll
    for (int kt = 0; kt < 8; ++kt) {
      float v[8];
#pragma unroll
      for (int i = 0; i < 8; ++i) v[i] = bf2f(bfrag[kt][i]) * ew;
#pragma unroll
      for (int i = 0; i < 8; ++i) {
        v[i] += __shfl_xor(v[i], 1, 64);
        v[i] += __shfl_xor(v[i], 2, 64);
        v[i] += __shfl_xor(v[i], 4, 64);
        v[i] += __shfl_xor(v[i], 8, 64);
      }
      if ((l & 15) == 0) {
        float* dst = slot + kt * 32 + (l >> 4) * 8;
#pragma unroll
        for (int i = 0; i < 8; ++i) dst[i] = v[i];
      }
    }
    if (l == 0) pesum[w][j] = es;
  }
  __syncthreads();

  // combine 8 waves -> global partials (ordinary coalesced stores, no atomics)
  const int G1 = batch[min(base + 127, N - 1)];
  const int nbg = min(G1 - G0 + 1, 4);
  const int jh = tid >> 8;   // 0 or 1
  const int d = tid & 255;
  for (int j = jh; j < nbg; j += 2) {
    float sum = 0.f;
#pragma unroll
    for (int wv = 0; wv < 8; ++wv) sum += pemb[(wv * 4 + j) * 256 + d];
    gpart[((size_t)blockIdx.x * 4 + j) * 256 + d] = sum;
    if (d == 0) {
      float ss = 0.f;
#pragma unroll
      for (int wv = 0; wv < 8; ++wv) ss += pesum[wv][j];
      gpsum[blockIdx.x * 4 + j] = ss;
    }
  }
}

// -------- Kernel D: reduce partials -> emb, normalize, project -------------
__global__ __launch_bounds__(256) void reduce_proj_kernel(
    const float* __restrict__ gpart, const float* __restrict__ gpsum,
    const int* __restrict__ batch, const int* __restrict__ segstart,
    const float* __restrict__ Wp, const float* __restrict__ bp,
    float* __restrict__ ctx, int N) {
  __shared__ float er[HH];
  const int g = blockIdx.x;
  const int t = threadIdx.x;
  const int n0 = segstart[g];
  const int n1 = segstart[g + 1];
  float emb = 0.f, es = 0.f;
  if (n1 > n0) {
    const int br0 = n0 >> 7;
    const int br1 = (n1 - 1) >> 7;
    for (int b = br0; b <= br1; ++b) {
      const int g0b = batch[b << 7];
      const int g1b = batch[min((b << 7) + 127, N - 1)];
      const int j = g - g0b;
      if (j >= 0 && j <= min(g1b - g0b, 3)) {
        emb += gpart[((size_t)b * 4 + j) * 256 + t];
        es += gpsum[b * 4 + j];
      }
    }
  }
  const float inv = (es > 0.f) ? 1.f / es : 0.f;
  er[t] = emb * inv;
  __syncthreads();
  float acc = bp[t];
#pragma unroll 4
  for (int k = 0; k < HH; ++k) {
    acc = fmaf(er[k], Wp[(size_t)k * HH + t], acc);
  }
  ctx[(size_t)g * HH + t] = acc;
}

// ---------------- Kernel E: out[n,:] = ctx[batch[n],:] ----------------
__global__ __launch_bounds__(256) void gather_kernel(
    const float4* __restrict__ ctx4, const int* __restrict__ batch,
    float4* __restrict__ out4, long long total4) {
  const long long gid = (long long)blockIdx.x * 256 + threadIdx.x;
  if (gid >= total4) return;
  const int n = (int)(gid >> 6);  // 64 float4 per row
  const int q = (int)(gid & 63);
  out4[gid] = ctx4[(size_t)batch[n] * 64 + q];
}

extern "C" void kernel_launch(void* const* d_in, const int* in_sizes, int n_in,
                              void* d_out, int out_size, void* d_ws, size_t ws_size,
                              hipStream_t stream) {
  const float* x = (const float*)d_in[0];
  const int* batch = (const int*)d_in[1];
  const float* W1 = (const float*)d_in[2];
  const float* b1 = (const float*)d_in[3];
  const float* W2 = (const float*)d_in[4];
  // d_in[5] = b2 (unused: softmax shift-invariant)
  const float* Wp = (const float*)d_in[6];
  const float* bp = (const float*)d_in[7];
  float* out = (float*)d_out;

  const int N = in_sizes[1];
  const int G = GG;
  const int nblk = (N + 127) / 128;

  // workspace layout (16B aligned)
  char* wsp = (char*)d_ws;
  short8* w1a = (short8*)wsp;              // 4096 short8 = 64 KB
  size_t off = 4096 * sizeof(short8);
  int* segstart = (int*)(wsp + off);       // G+1 ints
  off += (((size_t)(G + 1) * 4 + 15) & ~15ull);
  float* gpart = (float*)(wsp + off);      // nblk*4*256 floats (~6.4 MB)
  off += (size_t)nblk * 4 * HH * 4;
  float* gpsum = (float*)(wsp + off);      // nblk*4 floats
  off += (((size_t)nblk * 4 * 4 + 15) & ~15ull);
  float* ctx = (float*)(wsp + off);        // G*H floats

  // fragment W1
  w1frag_kernel<<<dim3(64), 64, 0, stream>>>(W1, w1a);
  // segment offsets
  {
    dim3 grid((N + 255) / 256);
    segstart_kernel<<<grid, 256, 0, stream>>>(batch, segstart, N, G);
  }
  // fused gate + block-local pool
  gate_pool_kernel<<<dim3(nblk), 512, 0, stream>>>(x, w1a, b1, W2, batch,
                                                   gpart, gpsum, N);
  // reduce partials + normalize + project
  reduce_proj_kernel<<<dim3(G), 256, 0, stream>>>(gpart, gpsum, batch,
                                                  segstart, Wp, bp, ctx, N);
  // gather/broadcast to nodes
  {
    const long long total4 = (long long)N * (HH / 4);
    dim3 grid((unsigned)((total4 + 255) / 256));
    gather_kernel<<<grid, 256, 0, stream>>>((const float4*)ctx, batch,
                                            (float4*)out, total4);
  }
}

// Round 6
// 164.922 us; speedup vs baseline: 1.2635x; 1.2635x over previous
//
#include <hip/hip_runtime.h>
#include <hip/hip_bf16.h>

#define HH 256   // hidden dim
#define HJ 128   // H/2
#define GG 512   // number of graphs

typedef __attribute__((ext_vector_type(8))) short short8;
typedef __attribute__((ext_vector_type(4))) float f32x4;

static __device__ __forceinline__ short f2bf(float f) {
  // round-to-nearest-even fp32 -> bf16 (inputs are finite)
  unsigned u = __builtin_bit_cast(unsigned, f);
  unsigned r = (u + 0x7FFFu + ((u >> 16) & 1u)) >> 16;
  return (short)r;
}

// ---------------- Kernel 0: pre-fragment W1^T into MFMA A-operand order ----
// w1a[kt*8+jt][lane] = 8 bf16: A[m=j][k] with j = jt*16+(l&15), k = kt*32+(l>>4)*8+i
__global__ __launch_bounds__(64) void w1frag_kernel(
    const float* __restrict__ W1, short8* __restrict__ w1a) {
  const int l = threadIdx.x;
  const int kt = blockIdx.x >> 3;
  const int jt = blockIdx.x & 7;
  const int j = jt * 16 + (l & 15);
  const int kb = kt * 32 + (l >> 4) * 8;
  short8 v;
#pragma unroll
  for (int i = 0; i < 8; ++i) v[i] = f2bf(W1[(size_t)(kb + i) * HJ + j]);
  w1a[blockIdx.x * 64 + l] = v;
}

// ---------------- segment offsets from sorted batch ----------------
__global__ __launch_bounds__(256) void segstart_kernel(
    const int* __restrict__ batch, int* __restrict__ segstart, int N, int G) {
  const int n = blockIdx.x * 256 + threadIdx.x;
  if (n >= N) return;
  const int b = batch[n];
  const int p = (n == 0) ? -1 : batch[n - 1];
  for (int g = p + 1; g <= b; ++g) segstart[g] = n;
  if (n == N - 1) {
    for (int g = b + 1; g <= G; ++g) segstart[g] = N;
  }
}

// ---------------- Kernel A: fused gate MLP + LDS-transpose pool ------------
// s[n] = tanh(x@W1+b1)@W2 (b2 dropped), e = exp(s) (max-free, |s|<=~10).
// Pool: x-tile round-trips through the dead A-fragment LDS (XOR-swizzled),
// then a channel-major sweep accumulates e-weighted sums per graph slot.
__global__ __launch_bounds__(512) void gate_pool_kernel(
    const float* __restrict__ x, const short8* __restrict__ w1a,
    const float* __restrict__ b1, const float* __restrict__ W2,
    const int* __restrict__ batch, const int* __restrict__ segstart,
    float* __restrict__ gpart, float* __restrict__ gpsum, int N) {
  __shared__ short8 alds[4096];  // 64 KB: A-frags, reused as x-tile, then red
  __shared__ float elds[128];
  __shared__ float pesum[8][4];
  const int tid = threadIdx.x;
  const int l = tid & 63;
  const int w = tid >> 6;  // wave 0..7

  // stage all A fragments (linear, coalesced, conflict-free)
#pragma unroll
  for (int i = 0; i < 8; ++i) alds[tid + i * 512] = w1a[tid + i * 512];

  const int base = blockIdx.x * 128;
  const int lnode = w * 16 + (l & 15);  // block-local node id
  const int node = base + lnode;
  const bool valid = node < N;
  const float* xp = x + (size_t)node * HH + (l >> 4) * 8;

  // B fragments: lane holds x[node][kt*32 + (l>>4)*8 + 0..7] as bf16
  short8 bfrag[8];
#pragma unroll
  for (int kt = 0; kt < 8; ++kt) {
    float4 f0 = make_float4(0.f, 0.f, 0.f, 0.f), f1 = f0;
    if (valid) {
      f0 = *reinterpret_cast<const float4*>(xp + kt * 32);
      f1 = *reinterpret_cast<const float4*>(xp + kt * 32 + 4);
    }
    short8 v;
    v[0] = f2bf(f0.x); v[1] = f2bf(f0.y); v[2] = f2bf(f0.z); v[3] = f2bf(f0.w);
    v[4] = f2bf(f1.x); v[5] = f2bf(f1.y); v[6] = f2bf(f1.z); v[7] = f2bf(f1.w);
    bfrag[kt] = v;
  }
  __syncthreads();

  f32x4 acc[8];
#pragma unroll
  for (int jt = 0; jt < 8; ++jt) acc[jt] = (f32x4)(0.f);

#pragma unroll
  for (int kt = 0; kt < 8; ++kt) {
#pragma unroll
    for (int jt = 0; jt < 8; ++jt) {
      acc[jt] = __builtin_amdgcn_mfma_f32_16x16x32_bf16(
          alds[(kt * 8 + jt) * 64 + l], bfrag[kt], acc[jt], 0, 0, 0);
    }
  }

  // epilogue: lane holds h[j][node] for j = jt*16 + (l>>4)*4 + r
  float sacc = 0.f;
  const int jb = (l >> 4) * 4;
#pragma unroll
  for (int jt = 0; jt < 8; ++jt) {
    const int j0 = jt * 16 + jb;
    const float4 bb = *reinterpret_cast<const float4*>(b1 + j0);
    const float4 ww = *reinterpret_cast<const float4*>(W2 + j0);
    // tanh(h) = 1 - 2/(exp(2h)+1)  (exact at +-inf, ~1e-7 err)
    float t0 = __expf(2.f * (acc[jt][0] + bb.x));
    float t1 = __expf(2.f * (acc[jt][1] + bb.y));
    float t2 = __expf(2.f * (acc[jt][2] + bb.z));
    float t3 = __expf(2.f * (acc[jt][3] + bb.w));
    sacc += (1.f - 2.f / (t0 + 1.f)) * ww.x;
    sacc += (1.f - 2.f / (t1 + 1.f)) * ww.y;
    sacc += (1.f - 2.f / (t2 + 1.f)) * ww.z;
    sacc += (1.f - 2.f / (t3 + 1.f)) * ww.w;
  }
  sacc += __shfl_xor(sacc, 16, 64);
  sacc += __shfl_xor(sacc, 32, 64);
  const float e = valid ? __expf(sacc) : 0.f;

  const int myg = batch[valid ? node : (N - 1)];
  const int G0 = batch[base];
  const int G1 = batch[min(base + 127, N - 1)];

  // per-wave, per-slot esum (16 shuffles/wave total -- cheap)
#pragma unroll
  for (int j = 0; j < 4; ++j) {
    float es = (myg == G0 + j) ? e : 0.f;
    es += __shfl_xor(es, 1, 64);
    es += __shfl_xor(es, 2, 64);
    es += __shfl_xor(es, 4, 64);
    es += __shfl_xor(es, 8, 64);
    if (l == 0) pesum[w][j] = es;
  }

  __syncthreads();  // all MFMA reads of alds done; reuse as bf16 x-tile

  // write x-tile: [node(128)][ch(256)] bf16, 16B chunks XOR-swizzled by node
  {
    char* xl = (char*)alds;
    const int swz = (lnode & 7) << 4;
#pragma unroll
    for (int kt = 0; kt < 8; ++kt) {
      const int off = lnode * 512 + ((kt * 64 + (l >> 4) * 16) ^ swz);
      *reinterpret_cast<short8*>(xl + off) = bfrag[kt];
    }
    if (l < 16) elds[lnode] = e;
  }
  __syncthreads();

  // slot node-ranges within block (block-uniform)
  int r[5];
  r[0] = 0;
#pragma unroll
  for (int j = 1; j <= 4; ++j) {
    const int gi = min(G0 + j, GG);
    r[j] = min(max(segstart[gi] - base, 0), 128);
  }

  // channel-major pooled sweep: thread (c2, hf) covers channels {2c2,2c2+1},
  // nodes [hf*32, hf*32+32) intersected with each slot range.
  const int c2 = tid & 127;
  const int hf = tid >> 7;
  const int nlo = hf * 32;
  const int nhi = nlo + 32;
  float2 pacc[4];
#pragma unroll
  for (int j = 0; j < 4; ++j) pacc[j] = make_float2(0.f, 0.f);
  {
    const char* xl = (const char*)alds;
#pragma unroll
    for (int j = 0; j < 4; ++j) {
      const int lo = max(nlo, r[j]);
      const int hi = min(nhi, r[j + 1]);
      for (int n = lo; n < hi; ++n) {
        const unsigned v = *reinterpret_cast<const unsigned*>(
            xl + n * 512 + ((c2 * 4) ^ ((n & 7) << 4)));
        const float ee = elds[n];  // wave-uniform -> LDS broadcast
        const float xlo = __builtin_bit_cast(float, v << 16);
        const float xhi = __builtin_bit_cast(float, v & 0xFFFF0000u);
        pacc[j].x = fmaf(xlo, ee, pacc[j].x);
        pacc[j].y = fmaf(xhi, ee, pacc[j].y);
      }
    }
  }
  __syncthreads();  // x-tile reads done; overlay reduction buffer

  // combine 4 node-quarters per slot, spill coalesced partials (no atomics)
  float2* red = (float2*)alds;  // [hf(4)][c2(128)]
  const int nbg = min(G1 - G0 + 1, 4);
  for (int j = 0; j < nbg; ++j) {
    red[hf * 128 + c2] = pacc[j];
    __syncthreads();
    if (tid < 128) {
      const float2 a = red[tid];
      const float2 b = red[128 + tid];
      const float2 c = red[256 + tid];
      const float2 d = red[384 + tid];
      float2 sv = make_float2(a.x + b.x + c.x + d.x, a.y + b.y + c.y + d.y);
      reinterpret_cast<float2*>(
          gpart + ((size_t)blockIdx.x * 4 + j) * 256)[tid] = sv;
      if (tid == 0) {
        float ss = 0.f;
#pragma unroll
        for (int wv = 0; wv < 8; ++wv) ss += pesum[wv][j];
        gpsum[blockIdx.x * 4 + j] = ss;
      }
    }
    __syncthreads();
  }
}

// -------- Kernel D: reduce partials -> emb, normalize, project -------------
__global__ __launch_bounds__(256) void reduce_proj_kernel(
    const float* __restrict__ gpart, const float* __restrict__ gpsum,
    const int* __restrict__ batch, const int* __restrict__ segstart,
    const float* __restrict__ Wp, const float* __restrict__ bp,
    float* __restrict__ ctx, int N) {
  __shared__ float er[HH];
  const int g = blockIdx.x;
  const int t = threadIdx.x;
  const int n0 = segstart[g];
  const int n1 = segstart[g + 1];
  float emb = 0.f, es = 0.f;
  if (n1 > n0) {
    const int br0 = n0 >> 7;
    const int br1 = (n1 - 1) >> 7;
    for (int b = br0; b <= br1; ++b) {
      const int g0b = batch[b << 7];
      const int g1b = batch[min((b << 7) + 127, N - 1)];
      const int j = g - g0b;
      if (j >= 0 && j <= min(g1b - g0b, 3)) {
        emb += gpart[((size_t)b * 4 + j) * 256 + t];
        es += gpsum[b * 4 + j];
      }
    }
  }
  const float inv = (es > 0.f) ? 1.f / es : 0.f;
  er[t] = emb * inv;
  __syncthreads();
  float acc = bp[t];
#pragma unroll 4
  for (int k = 0; k < HH; ++k) {
    acc = fmaf(er[k], Wp[(size_t)k * HH + t], acc);
  }
  ctx[(size_t)g * HH + t] = acc;
}

// ---------------- Kernel E: out[n,:] = ctx[batch[n],:] ----------------
__global__ __launch_bounds__(256) void gather_kernel(
    const float4* __restrict__ ctx4, const int* __restrict__ batch,
    float4* __restrict__ out4, long long total4) {
  const long long gid = (long long)blockIdx.x * 256 + threadIdx.x;
  if (gid >= total4) return;
  const int n = (int)(gid >> 6);  // 64 float4 per row
  const int q = (int)(gid & 63);
  out4[gid] = ctx4[(size_t)batch[n] * 64 + q];
}

extern "C" void kernel_launch(void* const* d_in, const int* in_sizes, int n_in,
                              void* d_out, int out_size, void* d_ws, size_t ws_size,
                              hipStream_t stream) {
  const float* x = (const float*)d_in[0];
  const int* batch = (const int*)d_in[1];
  const float* W1 = (const float*)d_in[2];
  const float* b1 = (const float*)d_in[3];
  const float* W2 = (const float*)d_in[4];
  // d_in[5] = b2 (unused: softmax shift-invariant)
  const float* Wp = (const float*)d_in[6];
  const float* bp = (const float*)d_in[7];
  float* out = (float*)d_out;

  const int N = in_sizes[1];
  const int G = GG;
  const int nblk = (N + 127) / 128;

  // workspace layout (16B aligned)
  char* wsp = (char*)d_ws;
  short8* w1a = (short8*)wsp;              // 4096 short8 = 64 KB
  size_t off = 4096 * sizeof(short8);
  int* segstart = (int*)(wsp + off);       // G+1 ints
  off += (((size_t)(G + 1) * 4 + 15) & ~15ull);
  float* gpart = (float*)(wsp + off);      // nblk*4*256 floats (~6.4 MB)
  off += (size_t)nblk * 4 * HH * 4;
  float* gpsum = (float*)(wsp + off);      // nblk*4 floats
  off += (((size_t)nblk * 4 * 4 + 15) & ~15ull);
  float* ctx = (float*)(wsp + off);        // G*H floats

  // fragment W1
  w1frag_kernel<<<dim3(64), 64, 0, stream>>>(W1, w1a);
  // segment offsets
  {
    dim3 grid((N + 255) / 256);
    segstart_kernel<<<grid, 256, 0, stream>>>(batch, segstart, N, G);
  }
  // fused gate + LDS-transpose pool
  gate_pool_kernel<<<dim3(nblk), 512, 0, stream>>>(x, w1a, b1, W2, batch,
                                                   segstart, gpart, gpsum, N);
  // reduce partials + normalize + project
  reduce_proj_kernel<<<dim3(G), 256, 0, stream>>>(gpart, gpsum, batch,
                                                  segstart, Wp, bp, ctx, N);
  // gather/broadcast to nodes
  {
    const long long total4 = (long long)N * (HH / 4);
    dim3 grid((unsigned)((total4 + 255) / 256));
    gather_kernel<<<grid, 256, 0, stream>>>((const float4*)ctx, batch,
                                            (float4*)out, total4);
  }
}

// Round 7
// 129.181 us; speedup vs baseline: 1.6131x; 1.2767x over previous
//
#include <hip/hip_runtime.h>
#include <hip/hip_bf16.h>

#define HH 256   // hidden dim
#define HJ 128   // H/2
#define GG 512   // number of graphs

typedef __attribute__((ext_vector_type(8))) short short8;
typedef __attribute__((ext_vector_type(4))) float f32x4;

static __device__ __forceinline__ short f2bf(float f) {
  // round-to-nearest-even fp32 -> bf16 (inputs are finite)
  unsigned u = __builtin_bit_cast(unsigned, f);
  unsigned r = (u + 0x7FFFu + ((u >> 16) & 1u)) >> 16;
  return (short)r;
}

// ---------------- Kernel 0: pre-fragment W1^T into MFMA A-operand order ----
// w1a[kt*8+jt][lane] = 8 bf16: A[m=j][k] with j = jt*16+(l&15), k = kt*32+(l>>4)*8+i
__global__ __launch_bounds__(64) void w1frag_kernel(
    const float* __restrict__ W1, short8* __restrict__ w1a) {
  const int l = threadIdx.x;
  const int kt = blockIdx.x >> 3;
  const int jt = blockIdx.x & 7;
  const int j = jt * 16 + (l & 15);
  const int kb = kt * 32 + (l >> 4) * 8;
  short8 v;
#pragma unroll
  for (int i = 0; i < 8; ++i) v[i] = f2bf(W1[(size_t)(kb + i) * HJ + j]);
  w1a[blockIdx.x * 64 + l] = v;
}

// ---------------- segment offsets from sorted batch ----------------
__global__ __launch_bounds__(256) void segstart_kernel(
    const int* __restrict__ batch, int* __restrict__ segstart, int N, int G) {
  const int n = blockIdx.x * 256 + threadIdx.x;
  if (n >= N) return;
  const int b = batch[n];
  const int p = (n == 0) ? -1 : batch[n - 1];
  for (int g = p + 1; g <= b; ++g) segstart[g] = n;
  if (n == N - 1) {
    for (int g = b + 1; g <= G; ++g) segstart[g] = N;
  }
}

// ---------------- Fused kernel: one block per graph ------------------------
// Per graph g (contiguous node range [n0,n1), batch sorted):
//   tile nodes by 128: gate MLP via MFMA -> e=exp(s) (b2 dropped, max-free)
//   channel-major LDS sweep accumulates emb_c = sum e_n * x[n,c]
//   normalize by esum, project (emb@Wp+bp), write ctx row to all graph nodes.
__global__ __launch_bounds__(512) void fused_kernel(
    const float* __restrict__ x, const short8* __restrict__ w1a,
    const float* __restrict__ b1, const float* __restrict__ W2,
    const int* __restrict__ segstart, const float* __restrict__ Wp,
    const float* __restrict__ bp, float4* __restrict__ out4, int N) {
  __shared__ short8 alds[4096];   // 64 KB: A-fragments, resident
  __shared__ short8 xlds[4096];   // 64 KB: bf16 x-tile [128][256], swizzled
  __shared__ float elds[128];
  __shared__ float esred[8];
  __shared__ float qredf[4][HH];  // quarter partials
  __shared__ float er[HH];        // normalized emb
  __shared__ float pr[2][HH];     // projection halves
  __shared__ float ctxl[HH];      // final context row

  const int tid = threadIdx.x;
  const int l = tid & 63;
  const int w = tid >> 6;  // wave 0..7
  const int g = blockIdx.x;

  // stage A fragments (linear, coalesced, conflict-free)
#pragma unroll
  for (int i = 0; i < 8; ++i) alds[tid + i * 512] = w1a[tid + i * 512];

  const int n0 = segstart[g];
  const int n1 = segstart[g + 1];
  const int cnt = n1 - n0;
  if (cnt <= 0) return;  // block-uniform, before any __syncthreads

  const int ntiles = (cnt + 127) >> 7;
  const int lnode = w * 16 + (l & 15);  // tile-local node id 0..127
  const int koff = (l >> 4) * 8;        // 0,8,16,24
  const int swz = (lnode & 7) << 4;

  // sweep mapping: channel pair + node quarter
  const int c2 = tid & 127;
  const int qh = tid >> 7;

  float2 pacc = make_float2(0.f, 0.f);
  float es_acc = 0.f;

  float4 ra[8], rb[8];
  // prologue: issue loads for tile 0
  {
    const int node = n0 + lnode;
    const bool v = node < n1;
    const float* xp = x + (size_t)node * HH + koff;
#pragma unroll
    for (int kt = 0; kt < 8; ++kt) {
      ra[kt] = v ? *reinterpret_cast<const float4*>(xp + kt * 32)
                 : make_float4(0.f, 0.f, 0.f, 0.f);
      rb[kt] = v ? *reinterpret_cast<const float4*>(xp + kt * 32 + 4)
                 : make_float4(0.f, 0.f, 0.f, 0.f);
    }
  }
  __syncthreads();  // A staged

  for (int t = 0; t < ntiles; ++t) {
    // convert raw floats -> bf16 B-fragments
    short8 bfrag[8];
#pragma unroll
    for (int kt = 0; kt < 8; ++kt) {
      short8 v;
      v[0] = f2bf(ra[kt].x); v[1] = f2bf(ra[kt].y);
      v[2] = f2bf(ra[kt].z); v[3] = f2bf(ra[kt].w);
      v[4] = f2bf(rb[kt].x); v[5] = f2bf(rb[kt].y);
      v[6] = f2bf(rb[kt].z); v[7] = f2bf(rb[kt].w);
      bfrag[kt] = v;
    }

    // issue next tile's loads (hidden under MFMA + sweep)
    if (t + 1 < ntiles) {
      const int node = n0 + (t + 1) * 128 + lnode;
      const bool v = node < n1;
      const float* xp = x + (size_t)node * HH + koff;
#pragma unroll
      for (int kt = 0; kt < 8; ++kt) {
        ra[kt] = v ? *reinterpret_cast<const float4*>(xp + kt * 32)
                   : make_float4(0.f, 0.f, 0.f, 0.f);
        rb[kt] = v ? *reinterpret_cast<const float4*>(xp + kt * 32 + 4)
                   : make_float4(0.f, 0.f, 0.f, 0.f);
      }
    }

    // gate GEMM: h[j][node] tiles
    f32x4 acc[8];
#pragma unroll
    for (int jt = 0; jt < 8; ++jt) acc[jt] = (f32x4)(0.f);
#pragma unroll
    for (int kt = 0; kt < 8; ++kt) {
#pragma unroll
      for (int jt = 0; jt < 8; ++jt) {
        acc[jt] = __builtin_amdgcn_mfma_f32_16x16x32_bf16(
            alds[(kt * 8 + jt) * 64 + l], bfrag[kt], acc[jt], 0, 0, 0);
      }
    }

    // epilogue: s = sum_j tanh(h_j + b1_j) * W2_j ; e = exp(s)
    float sacc = 0.f;
    const int jb = (l >> 4) * 4;
#pragma unroll
    for (int jt = 0; jt < 8; ++jt) {
      const int j0 = jt * 16 + jb;
      const float4 bb = *reinterpret_cast<const float4*>(b1 + j0);
      const float4 ww = *reinterpret_cast<const float4*>(W2 + j0);
      float t0 = __expf(2.f * (acc[jt][0] + bb.x));
      float t1 = __expf(2.f * (acc[jt][1] + bb.y));
      float t2 = __expf(2.f * (acc[jt][2] + bb.z));
      float t3 = __expf(2.f * (acc[jt][3] + bb.w));
      sacc += (1.f - 2.f / (t0 + 1.f)) * ww.x;
      sacc += (1.f - 2.f / (t1 + 1.f)) * ww.y;
      sacc += (1.f - 2.f / (t2 + 1.f)) * ww.z;
      sacc += (1.f - 2.f / (t3 + 1.f)) * ww.w;
    }
    sacc += __shfl_xor(sacc, 16, 64);
    sacc += __shfl_xor(sacc, 32, 64);
    const int node = n0 + t * 128 + lnode;
    const float e = (node < n1) ? __expf(sacc) : 0.f;

    // per-wave esum contribution (nodes live in lanes 0..15)
    {
      float ew = (l < 16) ? e : 0.f;
      ew += __shfl_xor(ew, 1, 64);
      ew += __shfl_xor(ew, 2, 64);
      ew += __shfl_xor(ew, 4, 64);
      ew += __shfl_xor(ew, 8, 64);
      es_acc += ew;  // valid on lanes 0..15 (l==0 used later)
    }

    __syncthreads();  // previous sweep done: x-tile free to overwrite

    // write bf16 x-tile (XOR-swizzled by node) + e
    {
      char* xl = (char*)xlds;
#pragma unroll
      for (int kt = 0; kt < 8; ++kt) {
        const int off = lnode * 512 + ((kt * 64 + koff * 2) ^ swz);
        *reinterpret_cast<short8*>(xl + off) = bfrag[kt];
      }
      if (l < 16) elds[lnode] = e;
    }
    __syncthreads();

    // channel-major sweep: thread (c2, qh) covers channels {2c2,2c2+1},
    // nodes [qh*32, qh*32+32). Invalid nodes have e=0.
    {
      const char* xl = (const char*)xlds;
#pragma unroll 8
      for (int m = 0; m < 32; ++m) {
        const int n = qh * 32 + m;
        const unsigned v = *reinterpret_cast<const unsigned*>(
            xl + n * 512 + ((c2 * 4) ^ ((n & 7) << 4)));
        const float ee = elds[n];
        const float xlo = __builtin_bit_cast(float, v << 16);
        const float xhi = __builtin_bit_cast(float, v & 0xFFFF0000u);
        pacc.x = fmaf(xlo, ee, pacc.x);
        pacc.y = fmaf(xhi, ee, pacc.y);
      }
    }
  }

  // combine quarter partials + esum
  qredf[qh][c2 * 2] = pacc.x;
  qredf[qh][c2 * 2 + 1] = pacc.y;
  if (l == 0) esred[w] = es_acc;
  __syncthreads();

  if (tid < HH) {
    float es = 0.f;
#pragma unroll
    for (int wv = 0; wv < 8; ++wv) es += esred[wv];
    const float inv = (es > 0.f) ? 1.f / es : 0.f;
    const float emb =
        qredf[0][tid] + qredf[1][tid] + qredf[2][tid] + qredf[3][tid];
    er[tid] = emb * inv;
  }
  __syncthreads();

  // projection: ctx = er @ Wp + bp, split over k-halves
  {
    const int c = tid & 255;
    const int h = tid >> 8;
    float p = 0.f;
    const float* wp = Wp + (size_t)h * 128 * HH + c;
#pragma unroll 4
    for (int k = 0; k < 128; ++k) {
      p = fmaf(er[h * 128 + k], wp[(size_t)k * HH], p);
    }
    pr[h][c] = p;
  }
  __syncthreads();
  if (tid < HH) {
    ctxl[tid] = pr[0][tid] + pr[1][tid] + bp[tid];
  }
  __syncthreads();

  // broadcast ctx row to all nodes of the graph (coalesced 1KB/wave rows)
  {
    const int q = tid & 63;
    const int r = tid >> 6;
    const float4 cv = reinterpret_cast<const float4*>(ctxl)[q];
    for (int n = n0 + r; n < n1; n += 8) {
      out4[(size_t)n * 64 + q] = cv;
    }
  }
}

extern "C" void kernel_launch(void* const* d_in, const int* in_sizes, int n_in,
                              void* d_out, int out_size, void* d_ws, size_t ws_size,
                              hipStream_t stream) {
  const float* x = (const float*)d_in[0];
  const int* batch = (const int*)d_in[1];
  const float* W1 = (const float*)d_in[2];
  const float* b1 = (const float*)d_in[3];
  const float* W2 = (const float*)d_in[4];
  // d_in[5] = b2 (unused: softmax shift-invariant)
  const float* Wp = (const float*)d_in[6];
  const float* bp = (const float*)d_in[7];
  float* out = (float*)d_out;

  const int N = in_sizes[1];
  const int G = GG;

  // workspace layout (16B aligned)
  char* wsp = (char*)d_ws;
  short8* w1a = (short8*)wsp;           // 4096 short8 = 64 KB
  size_t off = 4096 * sizeof(short8);
  int* segstart = (int*)(wsp + off);    // G+1 ints

  // fragment W1
  w1frag_kernel<<<dim3(64), 64, 0, stream>>>(W1, w1a);
  // segment offsets
  {
    dim3 grid((N + 255) / 256);
    segstart_kernel<<<grid, 256, 0, stream>>>(batch, segstart, N, G);
  }
  // fused gate + pool + project + broadcast
  fused_kernel<<<dim3(G), 512, 0, stream>>>(x, w1a, b1, W2, segstart, Wp, bp,
                                            (float4*)out, N);
}